// Round 7
// baseline (378.749 us; speedup 1.0000x reference)
//
#include <hip/hip_runtime.h>

typedef unsigned short u16;
typedef unsigned int u32;
typedef short bf16x8 __attribute__((ext_vector_type(8)));
typedef float f32x4 __attribute__((ext_vector_type(4)));
typedef unsigned int u32x2 __attribute__((ext_vector_type(2)));
typedef unsigned int u32x4 __attribute__((ext_vector_type(4)));

#define D_MODEL 1024
#define NH 16
#define DK 64
#define DFF 4096
#define BATCH 2
#define SEQ 2048
#define BL (BATCH*SEQ)
#define NQKV 3072
// fold (1/sqrt(64)) * log2(e) into Q so softmax is raw exp2 (v_exp_f32)
#define Q_SCALE 0.18033688011f

__device__ __forceinline__ float bfraw2f(u16 u) {
    union { u32 i; float f; } c; c.i = ((u32)u) << 16; return c.f;
}
__device__ __forceinline__ u16 f2bfraw(float f) {
    union { float f; u32 i; } c; c.f = f;
    u32 i = c.i;
    u32 lsb = (i >> 16) & 1u;
    i += 0x7fffu + lsb;
    return (u16)(i >> 16);
}
__device__ __forceinline__ u32 fasu(float f) {
    union { float f; u32 i; } c; c.f = f; return c.i;
}
// pack two f32 -> (bf16(hi)<<16)|bf16(lo), round-to-nearest via +0x8000
__device__ __forceinline__ u32 pack_bf2(float lo, float hi) {
    return __builtin_amdgcn_perm(fasu(hi) + 0x8000u, fasu(lo) + 0x8000u,
                                 0x07060302u);
}
// async global->LDS 16B per lane (dest = wave-uniform base + lane*16)
__device__ __forceinline__ void gload_lds16(const u16* g, u16* l) {
    __builtin_amdgcn_global_load_lds(
        (const __attribute__((address_space(1))) void*)g,
        (__attribute__((address_space(3))) void*)l, 16, 0, 0);
}

// ---------------- f32 -> bf16 cast ----------------
__global__ __launch_bounds__(256) void cast_f32_bf16(const float* __restrict__ in,
                                                     u16* __restrict__ out) {
    int i = (blockIdx.x * 256 + threadIdx.x) * 4;
    f32x4 v = *(const f32x4*)&in[i];
#pragma unroll
    for (int j = 0; j < 4; j++) out[i + j] = f2bfraw(v[j]);
}

// ---------------- transposes (f32 weights -> bf16 B^T layout) ----------------

__global__ __launch_bounds__(256) void transpose2d(const float* __restrict__ in,
                                                   u16* __restrict__ out,
                                                   int R, int C) {
    __shared__ u16 t[64][65];
    int c0 = blockIdx.x * 64, r0 = blockIdx.y * 64;
    int col = threadIdx.x & 63, rr = threadIdx.x >> 6;
    for (int i = rr; i < 64; i += 4)
        t[i][col] = f2bfraw(in[(size_t)(r0 + i) * C + c0 + col]);
    __syncthreads();
    for (int i = rr; i < 64; i += 4)
        out[(size_t)(c0 + i) * R + r0 + col] = t[col][i];
}

__global__ __launch_bounds__(256) void transpose_wqkv(const float* __restrict__ Wq,
                                                      const float* __restrict__ Wk,
                                                      const float* __restrict__ Wv,
                                                      u16* __restrict__ out) {
    __shared__ u16 t[64][65];
    int d0 = blockIdx.x * 64;
    int h = blockIdx.y;
    int ms = blockIdx.z;
    const float* W = (ms == 0) ? Wq : (ms == 1) ? Wk : Wv;
    const float* src = W + (size_t)h * D_MODEL * DK;
    int col = threadIdx.x & 63, rr = threadIdx.x >> 6;
    for (int i = rr; i < 64; i += 4)
        t[i][col] = f2bfraw(src[(size_t)(d0 + i) * DK + col]);
    __syncthreads();
    u16* dst = out + (size_t)(ms * 1024 + h * 64) * D_MODEL;
    for (int i = rr; i < 64; i += 4)
        dst[(size_t)i * D_MODEL + d0 + col] = t[col][i];
}

__global__ __launch_bounds__(256) void concat_bias(const float* __restrict__ bq,
                                                   const float* __restrict__ bk,
                                                   const float* __restrict__ bv,
                                                   float* __restrict__ out) {
    int i = blockIdx.x * 256 + threadIdx.x;
    out[i] = (i < 1024) ? bq[i] : (i < 2048) ? bk[i - 1024] : bv[i - 2048];
}

// ---------------- GEMM (m97 128x128): narrow-N ops + T1 XCD swizzle ---------
template <int OUT_F32, int RELU, int HASBIAS, int SPLITK, int SCALEQ, int VSTORE>
__global__ __launch_bounds__(256, 4) void gemm_bt(const u16* __restrict__ A,
                                                  const u16* __restrict__ Bt,
                                                  const float* __restrict__ bias,
                                                  void* __restrict__ Cout,
                                                  u16* __restrict__ vtout,
                                                  int M, int N, int K) {
    __shared__ __attribute__((aligned(16))) u16 As[128 * 64];
    __shared__ __attribute__((aligned(16))) u16 Bs[128 * 64];
    const int tid = threadIdx.x;
    const int lane = tid & 63, wid = tid >> 6;
    const int quad = lane >> 4, l16 = lane & 15;

    // T1: chunked XCD swizzle on (x,y); z (split-K) untouched. For grid
    // (32,8): each XCD owns one full n-column of 32 m-blocks -> B panel
    // fetched once per XCD L2 instead of 8x.
    int nwg = gridDim.x * gridDim.y;
    int flat = blockIdx.y * gridDim.x + blockIdx.x;
    if ((nwg & 7) == 0) {
        int q = nwg >> 3;
        flat = (flat & 7) * q + (flat >> 3);
    }
    const int m0 = (flat % gridDim.x) * 128;
    const int n0 = (flat / gridDim.x) * 128;

    const int z = (SPLITK > 1) ? blockIdx.z : 0;
    const int Klen = K / SPLITK;
    const int kend = (z + 1) * Klen;
    const int wm = (wid >> 1) * 64, wn = (wid & 1) * 64;

    f32x4 acc[4][4];
#pragma unroll
    for (int i = 0; i < 4; i++)
#pragma unroll
        for (int j = 0; j < 4; j++) acc[i][j] = (f32x4){0.f, 0.f, 0.f, 0.f};

    const int srow = lane >> 3, scol = (lane & 7) * 8;

    for (int kb = z * Klen; kb < kend; kb += 64) {
#pragma unroll
        for (int p = 0; p < 4; p++) {
            int c = wid * 4 + p;
            int row = c * 8 + srow;
            gload_lds16(&A[(size_t)(m0 + row) * K + kb + scol], &As[c * 512]);
            gload_lds16(&Bt[(size_t)(n0 + row) * K + kb + scol], &Bs[c * 512]);
        }
        __syncthreads();
#pragma unroll
        for (int kh = 0; kh < 2; kh++) {
            bf16x8 af[4], bf[4];
#pragma unroll
            for (int t = 0; t < 4; t++) {
                af[t] = *(const bf16x8*)&As[(wm + t * 16 + l16) * 64 + kh * 32 + quad * 8];
                bf[t] = *(const bf16x8*)&Bs[(wn + t * 16 + l16) * 64 + kh * 32 + quad * 8];
            }
#pragma unroll
            for (int i = 0; i < 4; i++)
#pragma unroll
                for (int j = 0; j < 4; j++)
                    acc[i][j] = __builtin_amdgcn_mfma_f32_16x16x32_bf16(
                        af[i], bf[j], acc[i][j], 0, 0, 0);
        }
        __syncthreads();
    }

    float* outf = (float*)Cout + (size_t)z * M * N;
#pragma unroll
    for (int i = 0; i < 4; i++) {
#pragma unroll
        for (int j = 0; j < 4; j++) {
#pragma unroll
            for (int r = 0; r < 4; r++) {
                int row = m0 + wm + i * 16 + quad * 4 + r;
                int col = n0 + wn + j * 16 + l16;
                float v = acc[i][j][r];
                if (HASBIAS) v += bias[col];
                if (RELU) v = v > 0.f ? v : 0.f;
                if (SCALEQ && col < 1024) v *= Q_SCALE;
                if (OUT_F32)
                    outf[(size_t)row * N + col] = v;
                else
                    ((u16*)Cout)[(size_t)row * N + col] = f2bfraw(v);
            }
        }
    }
}

// ---------------- GEMM v5: m201-style 8-phase 256x256 -----------------------
// Units = (tile w, k-half kh, matrix) = 256 rows x 32 k = 16KB = 2 loads/thr.
// LDS slots [parity][kh] per matrix: 2x2x16KB x2 = 128KB.
// Per tile w, 4 phases (kh x n-half), each:
//   {ds_read frags | stage ONE unit | s_barrier | setprio1 16 MFMA setprio0
//    | s_barrier}
// Stage schedule: ph0:A(w+1,kh1) ph1:B(w+1,kh1) ph2:A(w+2,kh0) ph3:B(w+2,kh0).
// Counted wait ONCE per tile (vmcnt(4)); never vmcnt(0) mid-loop.
// SWIZZLE (r7 fix): for 64B rows, bank-group = (16*row + 4*ch) mod 32 depends
// on row&1 only; r6's ch^=(row&3) left lanes {r,r+4,r+8,r+12} of equal parity
// on ONE chunk slot = 4-way conflict on every frag read. Correct axis:
// ch ^= (row>>1)&3 -> equal-parity lanes take all 4 chunk values -> free 2-way.
// Applied on BOTH global source and LDS reads (rule 21, XOR involution).
template <int OUT_F32, int RELU, int HASBIAS, int SCALEQ, int VSTORE>
__global__ __launch_bounds__(512, 2) void gemm5(const u16* __restrict__ A,
                                                const u16* __restrict__ Bt,
                                                const float* __restrict__ bias,
                                                void* __restrict__ Cout,
                                                u16* __restrict__ vtout,
                                                int M, int N, int K) {
    __shared__ __attribute__((aligned(16))) u16 As[2][2][256 * 32];
    __shared__ __attribute__((aligned(16))) u16 Bs[2][2][256 * 32];
    const int tid = threadIdx.x;
    const int lane = tid & 63, wid = tid >> 6;
    const int quad = lane >> 4, l16 = lane & 15;

    int nwg = gridDim.x * gridDim.y;
    int flat = blockIdx.y * gridDim.x + blockIdx.x;
    if ((nwg & 7) == 0) {
        int q = nwg >> 3;
        flat = (flat & 7) * q + (flat >> 3);
    }
    const int m0 = (flat % gridDim.x) * 256;
    const int n0 = (flat / gridDim.x) * 256;

    const int NTt = K >> 6;               // BK=64 tiles
    const int wrow = (wid >> 2) * 128;    // 2 wave-rows x 4 wave-cols
    const int wcol = (wid & 3) * 64;

    f32x4 acc[8][4];
#pragma unroll
    for (int i = 0; i < 8; i++)
#pragma unroll
        for (int j = 0; j < 4; j++) acc[i][j] = (f32x4){0.f, 0.f, 0.f, 0.f};

    // stage one unit (256x32): linear LDS dest, source chunk ^= (row>>1)&3
    auto stageA = [&](int w, int kh) {
        if (w >= NTt) return;
        u16* dst = As[w & 1][kh];
#pragma unroll
        for (int p = 0; p < 2; p++) {
            int e = p * 512 + tid;
            int row = e >> 2, ch = e & 3;
            gload_lds16(&A[(size_t)(m0 + row) * K + (w << 6) + (kh << 5) +
                           (((ch ^ ((row >> 1) & 3))) << 3)],
                        &dst[e * 8]);
        }
    };
    auto stageB = [&](int w, int kh) {
        if (w >= NTt) return;
        u16* dst = Bs[w & 1][kh];
#pragma unroll
        for (int p = 0; p < 2; p++) {
            int e = p * 512 + tid;
            int row = e >> 2, ch = e & 3;
            gload_lds16(&Bt[(size_t)(n0 + row) * K + (w << 6) + (kh << 5) +
                            (((ch ^ ((row >> 1) & 3))) << 3)],
                        &dst[e * 8]);
        }
    };

    // prologue: units for tile0 kh0, tile0 kh1, tile1 kh0 (12 loads);
    // tile0 needs kh0+kh1 -> allow tile1-kh0's 4 loads outstanding.
    stageA(0, 0); stageB(0, 0);
    stageA(0, 1); stageB(0, 1);
    stageA(1, 0); stageB(1, 0);
    asm volatile("s_waitcnt vmcnt(4)" ::: "memory");
    __builtin_amdgcn_s_barrier();

    for (int w = 0; w < NTt; w++) {
        const u16* as0 = As[w & 1][0];
        const u16* as1 = As[w & 1][1];
        const u16* bs0 = Bs[w & 1][0];
        const u16* bs1 = Bs[w & 1][1];
        bf16x8 af[8], bf0, bf1;

        // ---- ph0: kh0, n-frags 0,1 ----
#pragma unroll
        for (int i = 0; i < 8; i++) {
            int ra = wrow + i * 16 + l16;
            af[i] = *(const bf16x8*)&as0[ra * 32 + ((quad ^ ((ra >> 1) & 3)) * 8)];
        }
        {
            int rb0 = wcol + l16, rb1 = wcol + 16 + l16;
            bf0 = *(const bf16x8*)&bs0[rb0 * 32 + ((quad ^ ((rb0 >> 1) & 3)) * 8)];
            bf1 = *(const bf16x8*)&bs0[rb1 * 32 + ((quad ^ ((rb1 >> 1) & 3)) * 8)];
        }
        stageA(w + 1, 1);
        __builtin_amdgcn_s_barrier();
        __builtin_amdgcn_s_setprio(1);
#pragma unroll
        for (int i = 0; i < 8; i++) {
            acc[i][0] = __builtin_amdgcn_mfma_f32_16x16x32_bf16(af[i], bf0, acc[i][0], 0, 0, 0);
            acc[i][1] = __builtin_amdgcn_mfma_f32_16x16x32_bf16(af[i], bf1, acc[i][1], 0, 0, 0);
        }
        __builtin_amdgcn_s_setprio(0);
        __builtin_amdgcn_s_barrier();

        // ---- ph1: kh0, n-frags 2,3 ----
        {
            int rb2 = wcol + 32 + l16, rb3 = wcol + 48 + l16;
            bf0 = *(const bf16x8*)&bs0[rb2 * 32 + ((quad ^ ((rb2 >> 1) & 3)) * 8)];
            bf1 = *(const bf16x8*)&bs0[rb3 * 32 + ((quad ^ ((rb3 >> 1) & 3)) * 8)];
        }
        stageB(w + 1, 1);
        __builtin_amdgcn_s_barrier();
        __builtin_amdgcn_s_setprio(1);
#pragma unroll
        for (int i = 0; i < 8; i++) {
            acc[i][2] = __builtin_amdgcn_mfma_f32_16x16x32_bf16(af[i], bf0, acc[i][2], 0, 0, 0);
            acc[i][3] = __builtin_amdgcn_mfma_f32_16x16x32_bf16(af[i], bf1, acc[i][3], 0, 0, 0);
        }
        __builtin_amdgcn_s_setprio(0);
        __builtin_amdgcn_s_barrier();

        // ---- ph2: kh1, n-frags 0,1 ----
#pragma unroll
        for (int i = 0; i < 8; i++) {
            int ra = wrow + i * 16 + l16;
            af[i] = *(const bf16x8*)&as1[ra * 32 + ((quad ^ ((ra >> 1) & 3)) * 8)];
        }
        {
            int rb0 = wcol + l16, rb1 = wcol + 16 + l16;
            bf0 = *(const bf16x8*)&bs1[rb0 * 32 + ((quad ^ ((rb0 >> 1) & 3)) * 8)];
            bf1 = *(const bf16x8*)&bs1[rb1 * 32 + ((quad ^ ((rb1 >> 1) & 3)) * 8)];
        }
        stageA(w + 2, 0);
        __builtin_amdgcn_s_barrier();
        __builtin_amdgcn_s_setprio(1);
#pragma unroll
        for (int i = 0; i < 8; i++) {
            acc[i][0] = __builtin_amdgcn_mfma_f32_16x16x32_bf16(af[i], bf0, acc[i][0], 0, 0, 0);
            acc[i][1] = __builtin_amdgcn_mfma_f32_16x16x32_bf16(af[i], bf1, acc[i][1], 0, 0, 0);
        }
        __builtin_amdgcn_s_setprio(0);
        __builtin_amdgcn_s_barrier();

        // ---- ph3: kh1, n-frags 2,3 ----
        {
            int rb2 = wcol + 32 + l16, rb3 = wcol + 48 + l16;
            bf0 = *(const bf16x8*)&bs1[rb2 * 32 + ((quad ^ ((rb2 >> 1) & 3)) * 8)];
            bf1 = *(const bf16x8*)&bs1[rb3 * 32 + ((quad ^ ((rb3 >> 1) & 3)) * 8)];
        }
        stageB(w + 2, 0);
        __builtin_amdgcn_s_barrier();
        __builtin_amdgcn_s_setprio(1);
#pragma unroll
        for (int i = 0; i < 8; i++) {
            acc[i][2] = __builtin_amdgcn_mfma_f32_16x16x32_bf16(af[i], bf0, acc[i][2], 0, 0, 0);
            acc[i][3] = __builtin_amdgcn_mfma_f32_16x16x32_bf16(af[i], bf1, acc[i][3], 0, 0, 0);
        }
        __builtin_amdgcn_s_setprio(0);
        // counted wait: tile w+1 landed; tile w+2's 4 loads stay in flight
        if (w + 2 < NTt) asm volatile("s_waitcnt vmcnt(4)" ::: "memory");
        else             asm volatile("s_waitcnt vmcnt(0)" ::: "memory");
        __builtin_amdgcn_s_barrier();
    }

    if (VSTORE && n0 >= 2048) {
        // V section -> vtout[b][dv][l], dv = col-2048, 4 consecutive l per store
#pragma unroll
        for (int i = 0; i < 8; i++) {
            int row0 = m0 + wrow + i * 16 + quad * 4;
            int bb = row0 >> 11, l = row0 & 2047;
#pragma unroll
            for (int j = 0; j < 4; j++) {
                int col = n0 + wcol + j * 16 + l16;
                float bv = HASBIAS ? bias[col] : 0.f;
                int dv = col - 2048;
                u32x2 w2;
                w2.x = pack_bf2(acc[i][j][0] + bv, acc[i][j][1] + bv);
                w2.y = pack_bf2(acc[i][j][2] + bv, acc[i][j][3] + bv);
                *(u32x2*)&vtout[((size_t)(bb * 1024 + dv)) * 2048 + l] = w2;
            }
        }
        return;
    }

    float* outf = (float*)Cout;
#pragma unroll
    for (int i = 0; i < 8; i++) {
#pragma unroll
        for (int j = 0; j < 4; j++) {
#pragma unroll
            for (int r = 0; r < 4; r++) {
                int row = m0 + wrow + i * 16 + quad * 4 + r;
                int col = n0 + wcol + j * 16 + l16;
                float v = acc[i][j][r];
                if (HASBIAS) v += bias[col];
                if (RELU) v = v > 0.f ? v : 0.f;
                if (SCALEQ && col < 1024) v *= Q_SCALE;
                if (OUT_F32)
                    outf[(size_t)row * N + col] = v;
                else
                    ((u16*)Cout)[(size_t)row * N + col] = f2bfraw(v);
            }
        }
    }
}

// ---------------- flash attention, S^T form, v3 -----------------------------
__global__ __launch_bounds__(512, 4) void attn_kernel(const u16* __restrict__ qkv,
                                                      const u16* __restrict__ vt,
                                                      u16* __restrict__ O) {
    __shared__ __attribute__((aligned(16))) u16 Ks[2][128 * 64]; // [k=128][dk=64], swz
    __shared__ __attribute__((aligned(16))) u16 Vs[64 * 128];    // [dv=64][k-permuted], swz

    const int tid = threadIdx.x;
    const int lane = tid & 63, wid = tid >> 6;
    const int quad = lane >> 4, l16 = lane & 15;
    const int sw = l16 & 7;  // row-swizzle key for all l16-row reads
    const int b = blockIdx.z, h = blockIdx.y;
    const int q0 = blockIdx.x * 128 + wid * 16;

    // Q fragments (B-operand: n=q=l16, k=quad*8+j); Q pre-scaled by Q_SCALE
    const size_t qrow = (size_t)(b * SEQ + q0 + l16) * NQKV + h * DK;
    const bf16x8 qf0 = *(const bf16x8*)&qkv[qrow + quad * 8];
    const bf16x8 qf1 = *(const bf16x8*)&qkv[qrow + 32 + quad * 8];

    const u16* Kbase = qkv + (size_t)(b * SEQ) * NQKV + D_MODEL + h * DK;
    const u16* Vbase = vt + (size_t)((b * NH + h) * DK) * SEQ;

    f32x4 oacc[4];
#pragma unroll
    for (int d = 0; d < 4; d++) oacc[d] = (f32x4){0.f, 0.f, 0.f, 0.f};
    float lr = 0.f;
    const f32x4 Z = {0.f, 0.f, 0.f, 0.f};

    // K tile stage: direct-to-LDS, source pre-swizzled (chunk ^ row&7)
    auto stage_k = [&](int kt2, int buf) {
#pragma unroll
        for (int p = 0; p < 2; p++) {
            int seg = p * 8 + wid;                   // 16 segments of 8 rows
            int row = seg * 8 + (lane >> 3);
            int chunk = (lane & 7) ^ (lane >> 3);    // row&7 == lane>>3
            gload_lds16(&Kbase[(size_t)(kt2 + row) * NQKV + chunk * 8],
                        &Ks[buf][seg * 512]);
        }
    };
    // V tile load to regs (reg-staged: permuted LDS write can't use gload_lds)
    bf16x8 vreg[2];
    auto load_v = [&](int kt2) {
#pragma unroll
        for (int p = 0; p < 2; p++) {
            int s = p * 512 + tid;
            vreg[p] = *(const bf16x8*)&Vbase[(size_t)(s >> 4) * SEQ + kt2 + (s & 15) * 8];
        }
    };
    stage_k(0, 0);
    load_v(0);

    for (int t = 0; t < SEQ / 128; t++) {
        const int kt = t * 128;
        // ---- write V(t) regs -> Vs, k-permuted + swizzled -------------------
#pragma unroll
        for (int p = 0; p < 2; p++) {
            int s = p * 512 + tid;
            int vr = s >> 4, vc = s & 15;
            int chunkA = (vc >> 2) * 4 + (vc & 1) * 2;
            int rem = ((vc >> 1) & 1) * 4;
            u32x4 kv = __builtin_bit_cast(u32x4, vreg[p]);
            *(u32x2*)&Vs[vr * 128 + ((chunkA ^ (vr & 7)) * 8) + rem] =
                (u32x2){kv.x, kv.y};
            *(u32x2*)&Vs[vr * 128 + (((chunkA + 1) ^ (vr & 7)) * 8) + rem] =
                (u32x2){kv.z, kv.w};
        }
        __syncthreads();  // K(t) landed (vmcnt drained), Vs visible to all waves

        // issue next tile's K-to-LDS + V-to-regs; drained at barrier2
        if (t + 1 < SEQ / 128) {
            stage_k(kt + 128, (t + 1) & 1);
            load_v(kt + 128);
        }

        const u16* kb = Ks[t & 1];

        // ---- S^T = K·Q^T : sacc[nt], k=nt*16+quad*4+r, q=l16 ----
        f32x4 sacc[8];
        __builtin_amdgcn_s_setprio(1);
#pragma unroll
        for (int nt = 0; nt < 8; nt++) {
            const u16* krow = &kb[(nt * 16 + l16) * 64];
            bf16x8 kf0 = *(const bf16x8*)&krow[(quad ^ sw) * 8];
            bf16x8 kf1 = *(const bf16x8*)&krow[((4 + quad) ^ sw) * 8];
            f32x4 s0 = __builtin_amdgcn_mfma_f32_16x16x32_bf16(kf0, qf0, Z, 0, 0, 0);
            sacc[nt] = __builtin_amdgcn_mfma_f32_16x16x32_bf16(kf1, qf1, s0, 0, 0, 0);
        }
        __builtin_amdgcn_s_setprio(0);

        // ---- softmax fully in-register: exp2, per-lane sum, pack bf16 ----
        u32 wreg[8][2];
#pragma unroll
        for (int nt = 0; nt < 8; nt++) {
            float p0 = __builtin_amdgcn_exp2f(sacc[nt][0]);
            float p1 = __builtin_amdgcn_exp2f(sacc[nt][1]);
            float p2 = __builtin_amdgcn_exp2f(sacc[nt][2]);
            float p3 = __builtin_amdgcn_exp2f(sacc[nt][3]);
            lr += (p0 + p1) + (p2 + p3);
            wreg[nt][0] = pack_bf2(p0, p1);
            wreg[nt][1] = pack_bf2(p2, p3);
        }

        // ---- O^T += V^T·P^T over permuted k: B-frag is lane-local ----
        __builtin_amdgcn_s_setprio(1);
#pragma unroll
        for (int ks = 0; ks < 4; ks++) {
            u32x4 pw = (u32x4){wreg[2 * ks][0], wreg[2 * ks][1],
                               wreg[2 * ks + 1][0], wreg[2 * ks + 1][1]};
            bf16x8 pf = __builtin_bit_cast(bf16x8, pw);
#pragma unroll
            for (int d = 0; d < 4; d++) {
                bf16x8 vf = *(const bf16x8*)&Vs[(d * 16 + l16) * 128 +
                                                (((ks * 4 + quad) ^ sw) * 8)];
                oacc[d] = __builtin_amdgcn_mfma_f32_16x16x32_bf16(vf, pf, oacc[d], 0, 0, 0);
            }
        }
        __builtin_amdgcn_s_setprio(0);
        __syncthreads();  // all waves done with Ks[t&1]/Vs before restage
    }

    // lane's lr covers its quad's 32 k's per tile; reduce across quads
    lr += __shfl_xor(lr, 16, 64);
    lr += __shfl_xor(lr, 32, 64);
    float iv = 1.f / lr;

    // O^T C-layout: col=q=l16, row=dv=d*16+quad*4+r -> b64 stores
    size_t row = (size_t)(b * SEQ + q0 + l16);
#pragma unroll
    for (int d = 0; d < 4; d++) {
        float o0 = oacc[d][0] * iv, o1 = oacc[d][1] * iv;
        float o2 = oacc[d][2] * iv, o3 = oacc[d][3] * iv;
        u32x2 w;
        w.x = ((u32)f2bfraw(o1) << 16) | f2bfraw(o0);
        w.y = ((u32)f2bfraw(o3) << 16) | f2bfraw(o2);
        *(u32x2*)&O[row * D_MODEL + h * DK + d * 16 + quad * 4] = w;
    }
}

// ---------------- LayerNorm(a + b + c), f32 residual stream ----------------
__global__ __launch_bounds__(256) void ln3_kernel(const float* __restrict__ xa,
                                                  const float* __restrict__ xb,
                                                  const float* __restrict__ xc,
                                                  const float* __restrict__ g,
                                                  const float* __restrict__ be,
                                                  u16* __restrict__ out_bf,
                                                  float* __restrict__ out_f) {
    int row = blockIdx.x;
    int tid = threadIdx.x;
    const float* pa = xa + (size_t)row * D_MODEL;
    const float* pb = xb + (size_t)row * D_MODEL;
    const float* pc = xc + (size_t)row * D_MODEL;
    int c = tid * 4;
    f32x4 av = *(const f32x4*)&pa[c];
    f32x4 bv = *(const f32x4*)&pb[c];
    f32x4 cv = *(const f32x4*)&pc[c];
    float v[4];
    float s = 0.f, ss = 0.f;
#pragma unroll
    for (int i = 0; i < 4; i++) {
        v[i] = av[i] + bv[i] + cv[i];
        s += v[i];
        ss += v[i] * v[i];
    }
#pragma unroll
    for (int off = 32; off; off >>= 1) {
        s += __shfl_down(s, off, 64);
        ss += __shfl_down(ss, off, 64);
    }
    __shared__ float red[8];
    int wid = tid >> 6, lane = tid & 63;
    if (lane == 0) { red[wid] = s; red[4 + wid] = ss; }
    __syncthreads();
    if (tid == 0) {
        red[0] = red[0] + red[1] + red[2] + red[3];
        red[4] = red[4] + red[5] + red[6] + red[7];
    }
    __syncthreads();
    float mu = red[0] * (1.f / D_MODEL);
    float var = red[4] * (1.f / D_MODEL) - mu * mu;
    float rs = rsqrtf(var + 1e-5f);
#pragma unroll
    for (int i = 0; i < 4; i++) {
        float o = (v[i] - mu) * rs * g[c + i] + be[c + i];
        if (out_f) out_f[(size_t)row * D_MODEL + c + i] = o;
        if (out_bf) out_bf[(size_t)row * D_MODEL + c + i] = f2bfraw(o);
    }
}

// ---------------- launch ----------------
extern "C" void kernel_launch(void* const* d_in, const int* in_sizes, int n_in,
                              void* d_out, int out_size, void* d_ws, size_t ws_size,
                              hipStream_t stream) {
    const float* x   = (const float*)d_in[0];
    const float* Wq  = (const float*)d_in[1];
    const float* bq  = (const float*)d_in[2];
    const float* Wk  = (const float*)d_in[3];
    const float* bk  = (const float*)d_in[4];
    const float* Wv  = (const float*)d_in[5];
    const float* bv  = (const float*)d_in[6];
    const float* Wo  = (const float*)d_in[7];
    const float* g1  = (const float*)d_in[8];
    const float* be1 = (const float*)d_in[9];
    const float* W1  = (const float*)d_in[10];
    const float* b1  = (const float*)d_in[11];
    const float* W2  = (const float*)d_in[12];
    const float* g2  = (const float*)d_in[13];
    const float* be2 = (const float*)d_in[14];

    char* w = (char*)d_ws;
    auto alloc = [&](size_t bytes) {
        char* p = w;
        w += (bytes + 255) & ~(size_t)255;
        return p;
    };
    u16* wqkv_t = (u16*)alloc((size_t)NQKV * D_MODEL * 2);
    u16* wo_t   = (u16*)alloc((size_t)D_MODEL * D_MODEL * 2);
    u16* w1_t   = (u16*)alloc((size_t)DFF * D_MODEL * 2);
    u16* w2_t   = (u16*)alloc((size_t)D_MODEL * DFF * 2);
    float* bqkv = (float*)alloc((size_t)NQKV * 4);
    u16* x_bf   = (u16*)alloc((size_t)BL * D_MODEL * 2);
    u16* qkvbuf = (u16*)alloc((size_t)BL * NQKV * 2);
    u16* vtbuf  = (u16*)alloc((size_t)BATCH * NH * DK * SEQ * 2);
    u16* obuf   = (u16*)alloc((size_t)BL * D_MODEL * 2);
    float* mha_p = (float*)alloc((size_t)2 * BL * D_MODEL * 4);  // split-K partials
    u16* h1_bf  = (u16*)alloc((size_t)BL * D_MODEL * 2);
    float* h1_f = (float*)alloc((size_t)BL * D_MODEL * 4);
    u16* ffa    = (u16*)alloc((size_t)BL * DFF * 2);
    float* ffb_p = (float*)alloc((size_t)2 * BL * D_MODEL * 4); // split-K partials

    cast_f32_bf16<<<dim3(BL * D_MODEL / 1024), 256, 0, stream>>>(x, x_bf);
    transpose_wqkv<<<dim3(16, 16, 3), 256, 0, stream>>>(Wq, Wk, Wv, wqkv_t);
    transpose2d<<<dim3(16, 16), 256, 0, stream>>>(Wo, wo_t, 1024, 1024);
    transpose2d<<<dim3(64, 16), 256, 0, stream>>>(W1, w1_t, 1024, 4096);
    transpose2d<<<dim3(16, 64), 256, 0, stream>>>(W2, w2_t, 4096, 1024);
    concat_bias<<<dim3(12), 256, 0, stream>>>(bq, bk, bv, bqkv);

    // QKV = x @ Wqkv^T + bias -> Q,K bf16 into qkvbuf; V transposed into vtbuf
    gemm5<0, 0, 1, 1, 1><<<dim3(16, 12), 512, 0, stream>>>(
        x_bf, wqkv_t, bqkv, qkvbuf, vtbuf, BL, NQKV, D_MODEL);
    // flash attention -> O bf16 [4096][1024]
    attn_kernel<<<dim3(16, 16, 2), 512, 0, stream>>>(qkvbuf, vtbuf, obuf);
    // mha partials = O @ Wo (split-K=2) -> f32 x2
    gemm_bt<1, 0, 0, 2, 0, 0><<<dim3(32, 8, 2), 256, 0, stream>>>(
        obuf, wo_t, nullptr, mha_p, nullptr, BL, D_MODEL, D_MODEL);
    // h1 = LN(x + mha_p0 + mha_p1)
    ln3_kernel<<<dim3(BL), 256, 0, stream>>>(x, mha_p, mha_p + (size_t)BL * D_MODEL,
                                             g1, be1, h1_bf, h1_f);
    // ffa = relu(h1 @ W1 + b1) -> bf16 [4096][4096]
    gemm5<0, 1, 1, 0, 0><<<dim3(16, 16), 512, 0, stream>>>(
        h1_bf, w1_t, b1, ffa, nullptr, BL, DFF, D_MODEL);
    // ffb partials = ffa @ W2 (split-K=2) -> f32 x2
    gemm_bt<1, 0, 0, 2, 0, 0><<<dim3(32, 8, 2), 256, 0, stream>>>(
        ffa, w2_t, nullptr, ffb_p, nullptr, BL, D_MODEL, DFF);
    // out = LN(h1 + ffb_p0 + ffb_p1)
    ln3_kernel<<<dim3(BL), 256, 0, stream>>>(h1_f, ffb_p, ffb_p + (size_t)BL * D_MODEL,
                                             g2, be2, nullptr, (float*)d_out);
}

// Round 8
// 358.952 us; speedup vs baseline: 1.0552x; 1.0552x over previous
//
#include <hip/hip_runtime.h>

typedef unsigned short u16;
typedef unsigned int u32;
typedef short bf16x8 __attribute__((ext_vector_type(8)));
typedef float f32x4 __attribute__((ext_vector_type(4)));
typedef unsigned int u32x2 __attribute__((ext_vector_type(2)));
typedef unsigned int u32x4 __attribute__((ext_vector_type(4)));

#define D_MODEL 1024
#define NH 16
#define DK 64
#define DFF 4096
#define BATCH 2
#define SEQ 2048
#define BL (BATCH*SEQ)
#define NQKV 3072
// fold (1/sqrt(64)) * log2(e) into Q so softmax is raw exp2 (v_exp_f32)
#define Q_SCALE 0.18033688011f

__device__ __forceinline__ float bfraw2f(u16 u) {
    union { u32 i; float f; } c; c.i = ((u32)u) << 16; return c.f;
}
__device__ __forceinline__ u16 f2bfraw(float f) {
    union { float f; u32 i; } c; c.f = f;
    u32 i = c.i;
    u32 lsb = (i >> 16) & 1u;
    i += 0x7fffu + lsb;
    return (u16)(i >> 16);
}
__device__ __forceinline__ u32 fasu(float f) {
    union { float f; u32 i; } c; c.f = f; return c.i;
}
// pack two f32 -> (bf16(hi)<<16)|bf16(lo), round-to-nearest via +0x8000
__device__ __forceinline__ u32 pack_bf2(float lo, float hi) {
    return __builtin_amdgcn_perm(fasu(hi) + 0x8000u, fasu(lo) + 0x8000u,
                                 0x07060302u);
}
// async global->LDS 16B per lane (dest = wave-uniform base + lane*16)
__device__ __forceinline__ void gload_lds16(const u16* g, u16* l) {
    __builtin_amdgcn_global_load_lds(
        (const __attribute__((address_space(1))) void*)g,
        (__attribute__((address_space(3))) void*)l, 16, 0, 0);
}

// ---------------- f32 -> bf16 cast ----------------
__global__ __launch_bounds__(256) void cast_f32_bf16(const float* __restrict__ in,
                                                     u16* __restrict__ out) {
    int i = (blockIdx.x * 256 + threadIdx.x) * 4;
    f32x4 v = *(const f32x4*)&in[i];
#pragma unroll
    for (int j = 0; j < 4; j++) out[i + j] = f2bfraw(v[j]);
}

// ---------------- merged weight prep: all transposes + bias concat ----------
// grid (1024, 1, 6), 256 thr. z=0..2: Wq/Wk/Wv per-head transpose into the
// fused [3072][1024] B^T layout (256 tiles each; z=0 blocks 256..267 also do
// the bias concat). z=3: Wo (1024x1024). z=4: W1 (1024x4096). z=5: W2
// (4096x1024). Replaces 5 launches with 1 (cuts launch-gap overhead).
__global__ __launch_bounds__(256) void prep_weights(
    const float* __restrict__ Wq, const float* __restrict__ Wk,
    const float* __restrict__ Wv, const float* __restrict__ Wo,
    const float* __restrict__ W1, const float* __restrict__ W2,
    const float* __restrict__ bq, const float* __restrict__ bk,
    const float* __restrict__ bv,
    u16* __restrict__ wqkv_t, u16* __restrict__ wo_t,
    u16* __restrict__ w1_t, u16* __restrict__ w2_t,
    float* __restrict__ bqkv) {
    __shared__ u16 t[64][65];
    const int z = blockIdx.z, bx = blockIdx.x;
    const int col = threadIdx.x & 63, rr = threadIdx.x >> 6;

    if (z < 3) {
        if (bx >= 256) {
            if (z == 0 && bx < 268) {
                int i = (bx - 256) * 256 + threadIdx.x;
                bqkv[i] = (i < 1024) ? bq[i]
                        : (i < 2048) ? bk[i - 1024] : bv[i - 2048];
            }
            return;
        }
        const int d0 = (bx & 15) * 64, h = bx >> 4;
        const float* W = (z == 0) ? Wq : (z == 1) ? Wk : Wv;
        const float* src = W + (size_t)h * D_MODEL * DK;
        for (int i = rr; i < 64; i += 4)
            t[i][col] = f2bfraw(src[(size_t)(d0 + i) * DK + col]);
        __syncthreads();
        u16* dst = wqkv_t + (size_t)(z * 1024 + h * 64) * D_MODEL;
        for (int i = rr; i < 64; i += 4)
            dst[(size_t)i * D_MODEL + d0 + col] = t[col][i];
        return;
    }

    const float* in; u16* out; int R, C;
    if (z == 3)      { in = Wo; out = wo_t; R = 1024; C = 1024; }
    else if (z == 4) { in = W1; out = w1_t; R = 1024; C = 4096; }
    else             { in = W2; out = w2_t; R = 4096; C = 1024; }
    const int ctiles = C >> 6;
    const int rt = bx / ctiles, ct = bx % ctiles;
    if (rt >= (R >> 6)) return;
    const int c0 = ct * 64, r0 = rt * 64;
    for (int i = rr; i < 64; i += 4)
        t[i][col] = f2bfraw(in[(size_t)(r0 + i) * C + c0 + col]);
    __syncthreads();
    for (int i = rr; i < 64; i += 4)
        out[(size_t)(c0 + i) * R + r0 + col] = t[col][i];
}

// ---------------- GEMM: C[M][N] = A[M][K] @ Bt[N][K]^T ----------------
// m97 structure (r2-exact, session-best): 128x128 tile, BK=64, unpadded LDS,
// global_load_lds width 16, NO XCD swizzle (r7 showed it wrecks A-panel L2
// reuse: FETCH 49->135MB).
// VSTORE: blocks with n0>=2048 (V section of QKV) store transposed into vtout
//         [b][h][dv][l] as 8B packed bf16.

template <int OUT_F32, int RELU, int HASBIAS, int SPLITK, int SCALEQ, int VSTORE>
__global__ __launch_bounds__(256, 4) void gemm_bt(const u16* __restrict__ A,
                                                  const u16* __restrict__ Bt,
                                                  const float* __restrict__ bias,
                                                  void* __restrict__ Cout,
                                                  u16* __restrict__ vtout,
                                                  int M, int N, int K) {
    __shared__ __attribute__((aligned(16))) u16 As[128 * 64];
    __shared__ __attribute__((aligned(16))) u16 Bs[128 * 64];
    const int tid = threadIdx.x;
    const int lane = tid & 63, wid = tid >> 6;
    const int quad = lane >> 4, l16 = lane & 15;
    const int m0 = blockIdx.x * 128, n0 = blockIdx.y * 128;
    const int z = (SPLITK > 1) ? blockIdx.z : 0;
    const int Klen = K / SPLITK;
    const int kend = (z + 1) * Klen;
    const int wm = (wid >> 1) * 64, wn = (wid & 1) * 64;

    f32x4 acc[4][4];
#pragma unroll
    for (int i = 0; i < 4; i++)
#pragma unroll
        for (int j = 0; j < 4; j++) acc[i][j] = (f32x4){0.f, 0.f, 0.f, 0.f};

    const int srow = lane >> 3, scol = (lane & 7) * 8;

    for (int kb = z * Klen; kb < kend; kb += 64) {
#pragma unroll
        for (int p = 0; p < 4; p++) {
            int c = wid * 4 + p;
            int row = c * 8 + srow;
            gload_lds16(&A[(size_t)(m0 + row) * K + kb + scol], &As[c * 512]);
            gload_lds16(&Bt[(size_t)(n0 + row) * K + kb + scol], &Bs[c * 512]);
        }
        __syncthreads();
#pragma unroll
        for (int kh = 0; kh < 2; kh++) {
            bf16x8 af[4], bf[4];
#pragma unroll
            for (int t = 0; t < 4; t++) {
                af[t] = *(const bf16x8*)&As[(wm + t * 16 + l16) * 64 + kh * 32 + quad * 8];
                bf[t] = *(const bf16x8*)&Bs[(wn + t * 16 + l16) * 64 + kh * 32 + quad * 8];
            }
#pragma unroll
            for (int i = 0; i < 4; i++)
#pragma unroll
                for (int j = 0; j < 4; j++)
                    acc[i][j] = __builtin_amdgcn_mfma_f32_16x16x32_bf16(
                        af[i], bf[j], acc[i][j], 0, 0, 0);
        }
        __syncthreads();
    }

    if (VSTORE && n0 >= 2048) {
        // V section -> vtout[b][dv][l], dv = col-2048, 4 consecutive l per store
#pragma unroll
        for (int i = 0; i < 4; i++) {
            int row0 = m0 + wm + i * 16 + quad * 4;
            int bb = row0 >> 11, l = row0 & 2047;
#pragma unroll
            for (int j = 0; j < 4; j++) {
                int col = n0 + wn + j * 16 + l16;
                float bv = HASBIAS ? bias[col] : 0.f;
                int dv = col - 2048;
                u32x2 w;
                w.x = pack_bf2(acc[i][j][0] + bv, acc[i][j][1] + bv);
                w.y = pack_bf2(acc[i][j][2] + bv, acc[i][j][3] + bv);
                *(u32x2*)&vtout[((size_t)(bb * 1024 + dv)) * 2048 + l] = w;
            }
        }
        return;
    }

    float* outf = (float*)Cout + (size_t)z * M * N;
#pragma unroll
    for (int i = 0; i < 4; i++) {
#pragma unroll
        for (int j = 0; j < 4; j++) {
#pragma unroll
            for (int r = 0; r < 4; r++) {
                int row = m0 + wm + i * 16 + quad * 4 + r;
                int col = n0 + wn + j * 16 + l16;
                float v = acc[i][j][r];
                if (HASBIAS) v += bias[col];
                if (RELU) v = v > 0.f ? v : 0.f;
                if (SCALEQ && col < 1024) v *= Q_SCALE;
                if (OUT_F32)
                    outf[(size_t)row * N + col] = v;
                else
                    ((u16*)Cout)[(size_t)row * N + col] = f2bfraw(v);
            }
        }
    }
}

// ---------------- flash attention, S^T form, v3 -----------------------------
// grid (SEQ/128, NH, BATCH); 8 waves x 512 threads; wave owns 16 q rows.
//  - P never touches LDS: PV's k-axis permuted per 32-slice (pi bijective),
//    V stored pre-permuted so PV B-frag = lane-local packed exp() output.
//  - K double-buffered via global_load_lds with pre-swizzled source.
//  - LDS = 2*16384 (K dbuf) + 16384 (V) = 49152 B.
__global__ __launch_bounds__(512, 4) void attn_kernel(const u16* __restrict__ qkv,
                                                      const u16* __restrict__ vt,
                                                      u16* __restrict__ O) {
    __shared__ __attribute__((aligned(16))) u16 Ks[2][128 * 64]; // [k=128][dk=64], swz
    __shared__ __attribute__((aligned(16))) u16 Vs[64 * 128];    // [dv=64][k-permuted], swz

    const int tid = threadIdx.x;
    const int lane = tid & 63, wid = tid >> 6;
    const int quad = lane >> 4, l16 = lane & 15;
    const int sw = l16 & 7;  // row-swizzle key for all l16-row reads
    const int b = blockIdx.z, h = blockIdx.y;
    const int q0 = blockIdx.x * 128 + wid * 16;

    // Q fragments (B-operand: n=q=l16, k=quad*8+j); Q pre-scaled by Q_SCALE
    const size_t qrow = (size_t)(b * SEQ + q0 + l16) * NQKV + h * DK;
    const bf16x8 qf0 = *(const bf16x8*)&qkv[qrow + quad * 8];
    const bf16x8 qf1 = *(const bf16x8*)&qkv[qrow + 32 + quad * 8];

    const u16* Kbase = qkv + (size_t)(b * SEQ) * NQKV + D_MODEL + h * DK;
    const u16* Vbase = vt + (size_t)((b * NH + h) * DK) * SEQ;

    f32x4 oacc[4];
#pragma unroll
    for (int d = 0; d < 4; d++) oacc[d] = (f32x4){0.f, 0.f, 0.f, 0.f};
    float lr = 0.f;
    const f32x4 Z = {0.f, 0.f, 0.f, 0.f};

    // K tile stage: direct-to-LDS, source pre-swizzled (chunk ^ row&7)
    auto stage_k = [&](int kt2, int buf) {
#pragma unroll
        for (int p = 0; p < 2; p++) {
            int seg = p * 8 + wid;                   // 16 segments of 8 rows
            int row = seg * 8 + (lane >> 3);
            int chunk = (lane & 7) ^ (lane >> 3);    // row&7 == lane>>3
            gload_lds16(&Kbase[(size_t)(kt2 + row) * NQKV + chunk * 8],
                        &Ks[buf][seg * 512]);
        }
    };
    // V tile load to regs (reg-staged: permuted LDS write can't use gload_lds)
    bf16x8 vreg[2];
    auto load_v = [&](int kt2) {
#pragma unroll
        for (int p = 0; p < 2; p++) {
            int s = p * 512 + tid;
            vreg[p] = *(const bf16x8*)&Vbase[(size_t)(s >> 4) * SEQ + kt2 + (s & 15) * 8];
        }
    };
    stage_k(0, 0);
    load_v(0);

    for (int t = 0; t < SEQ / 128; t++) {
        const int kt = t * 128;
        // ---- write V(t) regs -> Vs, k-permuted + swizzled -------------------
#pragma unroll
        for (int p = 0; p < 2; p++) {
            int s = p * 512 + tid;
            int vr = s >> 4, vc = s & 15;
            int chunkA = (vc >> 2) * 4 + (vc & 1) * 2;
            int rem = ((vc >> 1) & 1) * 4;
            u32x4 kv = __builtin_bit_cast(u32x4, vreg[p]);
            *(u32x2*)&Vs[vr * 128 + ((chunkA ^ (vr & 7)) * 8) + rem] =
                (u32x2){kv.x, kv.y};
            *(u32x2*)&Vs[vr * 128 + (((chunkA + 1) ^ (vr & 7)) * 8) + rem] =
                (u32x2){kv.z, kv.w};
        }
        __syncthreads();  // K(t) landed (vmcnt drained), Vs visible to all waves

        // issue next tile's K-to-LDS + V-to-regs; drained at barrier2
        if (t + 1 < SEQ / 128) {
            stage_k(kt + 128, (t + 1) & 1);
            load_v(kt + 128);
        }

        const u16* kb = Ks[t & 1];

        // ---- S^T = K·Q^T : sacc[nt], k=nt*16+quad*4+r, q=l16 ----
        f32x4 sacc[8];
        __builtin_amdgcn_s_setprio(1);
#pragma unroll
        for (int nt = 0; nt < 8; nt++) {
            const u16* krow = &kb[(nt * 16 + l16) * 64];
            bf16x8 kf0 = *(const bf16x8*)&krow[(quad ^ sw) * 8];
            bf16x8 kf1 = *(const bf16x8*)&krow[((4 + quad) ^ sw) * 8];
            f32x4 s0 = __builtin_amdgcn_mfma_f32_16x16x32_bf16(kf0, qf0, Z, 0, 0, 0);
            sacc[nt] = __builtin_amdgcn_mfma_f32_16x16x32_bf16(kf1, qf1, s0, 0, 0, 0);
        }
        __builtin_amdgcn_s_setprio(0);

        // ---- softmax fully in-register: exp2, per-lane sum, pack bf16 ----
        u32 wreg[8][2];
#pragma unroll
        for (int nt = 0; nt < 8; nt++) {
            float p0 = __builtin_amdgcn_exp2f(sacc[nt][0]);
            float p1 = __builtin_amdgcn_exp2f(sacc[nt][1]);
            float p2 = __builtin_amdgcn_exp2f(sacc[nt][2]);
            float p3 = __builtin_amdgcn_exp2f(sacc[nt][3]);
            lr += (p0 + p1) + (p2 + p3);
            wreg[nt][0] = pack_bf2(p0, p1);
            wreg[nt][1] = pack_bf2(p2, p3);
        }

        // ---- O^T += V^T·P^T over permuted k: B-frag is lane-local ----
        __builtin_amdgcn_s_setprio(1);
#pragma unroll
        for (int ks = 0; ks < 4; ks++) {
            u32x4 pw = (u32x4){wreg[2 * ks][0], wreg[2 * ks][1],
                               wreg[2 * ks + 1][0], wreg[2 * ks + 1][1]};
            bf16x8 pf = __builtin_bit_cast(bf16x8, pw);
#pragma unroll
            for (int d = 0; d < 4; d++) {
                bf16x8 vf = *(const bf16x8*)&Vs[(d * 16 + l16) * 128 +
                                                (((ks * 4 + quad) ^ sw) * 8)];
                oacc[d] = __builtin_amdgcn_mfma_f32_16x16x32_bf16(vf, pf, oacc[d], 0, 0, 0);
            }
        }
        __builtin_amdgcn_s_setprio(0);
        __syncthreads();  // all waves done with Ks[t&1]/Vs before restage
    }

    // lane's lr covers its quad's 32 k's per tile; reduce across quads
    lr += __shfl_xor(lr, 16, 64);
    lr += __shfl_xor(lr, 32, 64);
    float iv = 1.f / lr;

    // O^T C-layout: col=q=l16, row=dv=d*16+quad*4+r -> b64 stores
    size_t row = (size_t)(b * SEQ + q0 + l16);
#pragma unroll
    for (int d = 0; d < 4; d++) {
        float o0 = oacc[d][0] * iv, o1 = oacc[d][1] * iv;
        float o2 = oacc[d][2] * iv, o3 = oacc[d][3] * iv;
        u32x2 w;
        w.x = ((u32)f2bfraw(o1) << 16) | f2bfraw(o0);
        w.y = ((u32)f2bfraw(o3) << 16) | f2bfraw(o2);
        *(u32x2*)&O[row * D_MODEL + h * DK + d * 16 + quad * 4] = w;
    }
}

// ---------------- LayerNorm(a + b + c), f32 residual stream ----------------
__global__ __launch_bounds__(256) void ln3_kernel(const float* __restrict__ xa,
                                                  const float* __restrict__ xb,
                                                  const float* __restrict__ xc,
                                                  const float* __restrict__ g,
                                                  const float* __restrict__ be,
                                                  u16* __restrict__ out_bf,
                                                  float* __restrict__ out_f) {
    int row = blockIdx.x;
    int tid = threadIdx.x;
    const float* pa = xa + (size_t)row * D_MODEL;
    const float* pb = xb + (size_t)row * D_MODEL;
    const float* pc = xc + (size_t)row * D_MODEL;
    int c = tid * 4;
    f32x4 av = *(const f32x4*)&pa[c];
    f32x4 bv = *(const f32x4*)&pb[c];
    f32x4 cv = *(const f32x4*)&pc[c];
    float v[4];
    float s = 0.f, ss = 0.f;
#pragma unroll
    for (int i = 0; i < 4; i++) {
        v[i] = av[i] + bv[i] + cv[i];
        s += v[i];
        ss += v[i] * v[i];
    }
#pragma unroll
    for (int off = 32; off; off >>= 1) {
        s += __shfl_down(s, off, 64);
        ss += __shfl_down(ss, off, 64);
    }
    __shared__ float red[8];
    int wid = tid >> 6, lane = tid & 63;
    if (lane == 0) { red[wid] = s; red[4 + wid] = ss; }
    __syncthreads();
    if (tid == 0) {
        red[0] = red[0] + red[1] + red[2] + red[3];
        red[4] = red[4] + red[5] + red[6] + red[7];
    }
    __syncthreads();
    float mu = red[0] * (1.f / D_MODEL);
    float var = red[4] * (1.f / D_MODEL) - mu * mu;
    float rs = rsqrtf(var + 1e-5f);
#pragma unroll
    for (int i = 0; i < 4; i++) {
        float o = (v[i] - mu) * rs * g[c + i] + be[c + i];
        if (out_f) out_f[(size_t)row * D_MODEL + c + i] = o;
        if (out_bf) out_bf[(size_t)row * D_MODEL + c + i] = f2bfraw(o);
    }
}

// ---------------- launch ----------------
extern "C" void kernel_launch(void* const* d_in, const int* in_sizes, int n_in,
                              void* d_out, int out_size, void* d_ws, size_t ws_size,
                              hipStream_t stream) {
    const float* x   = (const float*)d_in[0];
    const float* Wq  = (const float*)d_in[1];
    const float* bq  = (const float*)d_in[2];
    const float* Wk  = (const float*)d_in[3];
    const float* bk  = (const float*)d_in[4];
    const float* Wv  = (const float*)d_in[5];
    const float* bv  = (const float*)d_in[6];
    const float* Wo  = (const float*)d_in[7];
    const float* g1  = (const float*)d_in[8];
    const float* be1 = (const float*)d_in[9];
    const float* W1  = (const float*)d_in[10];
    const float* b1  = (const float*)d_in[11];
    const float* W2  = (const float*)d_in[12];
    const float* g2  = (const float*)d_in[13];
    const float* be2 = (const float*)d_in[14];

    char* w = (char*)d_ws;
    auto alloc = [&](size_t bytes) {
        char* p = w;
        w += (bytes + 255) & ~(size_t)255;
        return p;
    };
    u16* wqkv_t = (u16*)alloc((size_t)NQKV * D_MODEL * 2);
    u16* wo_t   = (u16*)alloc((size_t)D_MODEL * D_MODEL * 2);
    u16* w1_t   = (u16*)alloc((size_t)DFF * D_MODEL * 2);
    u16* w2_t   = (u16*)alloc((size_t)D_MODEL * DFF * 2);
    float* bqkv = (float*)alloc((size_t)NQKV * 4);
    u16* x_bf   = (u16*)alloc((size_t)BL * D_MODEL * 2);
    u16* qkvbuf = (u16*)alloc((size_t)BL * NQKV * 2);
    u16* vtbuf  = (u16*)alloc((size_t)BATCH * NH * DK * SEQ * 2);
    u16* obuf   = (u16*)alloc((size_t)BL * D_MODEL * 2);
    float* mha_p = (float*)alloc((size_t)2 * BL * D_MODEL * 4);  // split-K partials
    u16* h1_bf  = (u16*)alloc((size_t)BL * D_MODEL * 2);
    float* h1_f = (float*)alloc((size_t)BL * D_MODEL * 4);
    u16* ffa    = (u16*)alloc((size_t)BL * DFF * 2);
    float* ffb_p = (float*)alloc((size_t)2 * BL * D_MODEL * 4); // split-K partials

    cast_f32_bf16<<<dim3(BL * D_MODEL / 1024), 256, 0, stream>>>(x, x_bf);
    prep_weights<<<dim3(1024, 1, 6), 256, 0, stream>>>(
        Wq, Wk, Wv, Wo, W1, W2, bq, bk, bv, wqkv_t, wo_t, w1_t, w2_t, bqkv);

    // QKV = x @ Wqkv^T + bias -> Q,K bf16 into qkvbuf; V transposed into vtbuf
    gemm_bt<0, 0, 1, 1, 1, 1><<<dim3(32, 24), 256, 0, stream>>>(
        x_bf, wqkv_t, bqkv, qkvbuf, vtbuf, BL, NQKV, D_MODEL);
    // flash attention -> O bf16 [4096][1024]
    attn_kernel<<<dim3(16, 16, 2), 512, 0, stream>>>(qkvbuf, vtbuf, obuf);
    // mha partials = O @ Wo (split-K=2) -> f32 x2
    gemm_bt<1, 0, 0, 2, 0, 0><<<dim3(32, 8, 2), 256, 0, stream>>>(
        obuf, wo_t, nullptr, mha_p, nullptr, BL, D_MODEL, D_MODEL);
    // h1 = LN(x + mha_p0 + mha_p1)
    ln3_kernel<<<dim3(BL), 256, 0, stream>>>(x, mha_p, mha_p + (size_t)BL * D_MODEL,
                                             g1, be1, h1_bf, h1_f);
    // ffa = relu(h1 @ W1 + b1) -> bf16 [4096][4096]
    gemm_bt<0, 1, 1, 1, 0, 0><<<dim3(32, 32), 256, 0, stream>>>(
        h1_bf, w1_t, b1, ffa, nullptr, BL, DFF, D_MODEL);
    // ffb partials = ffa @ W2 (split-K=2) -> f32 x2
    gemm_bt<1, 0, 0, 2, 0, 0><<<dim3(32, 8, 2), 256, 0, stream>>>(
        ffa, w2_t, nullptr, ffb_p, nullptr, BL, D_MODEL, DFF);
    // out = LN(h1 + ffb_p0 + ffb_p1)
    ln3_kernel<<<dim3(BL), 256, 0, stream>>>(h1_f, ffb_p, ffb_p + (size_t)BL * D_MODEL,
                                             g2, be2, nullptr, (float*)d_out);
}